// Round 5
// baseline (1214.066 us; speedup 1.0000x reference)
//
#include <hip/hip_runtime.h>

// RoiAlign (TF crop_and_resize style), fp32, NHWC.
// features: [B,H,W,C] = [2,64,64,256]; rois: [B,N,4] = [2,2000,4]
// out: [B,N,7,7,C]
//
// R6: XCC-ID-bound band queues.
// Scoreboard (kernel-chain time = dur_us - ~126us harness fill):
//   R2 direct gather + nt stores           ~91us   (best)
//   R3 blockIdx%8 y-banding                ~103us  (mapping assumption false)
//   R4 LDS binning, 8x staged              ~120us  (staging redundancy, 1 blk/CU)
//   R5 sorted-order consume                ~144us  (occupancy pad + indirection)
// Standing theory: R2 = 784MB reads + 200MB writes in 91us = 10.8 TB/s
// combined -> reads served by Infinity Cache (~14 TB/s), because every
// XCD L2 sees the full 8MB working set (2x 4MiB capacity) and thrashes.
// R3/R5 failed on ASSUMED block->XCD mapping / dispatch order. This
// version uses the HW-verified s_getreg(HW_REG_XCC_ID) [learn_hip m09]:
// blocks OBSERVE their XCD and pop work only from that XCD's band queue
// (band = batch*4 + y0>>4 -> 17 feature rows = 1.06MB, L2-resident).
// Work-stealing fallback after own band drains => correctness does not
// depend on XCC_ID at all (it is a pure locality hint). Slots store the
// GLOBAL row id, and the consume pass recomputes b,n,py,y0 from it, so
// there is no FP-consistency coupling between passes either.
// Inner row body is bit-identical to R2's proven loop; nt stores kept.
// Fallback to plain R2 kernel if ws_size < ~450 KB.

#define POOL   7
#define NBANDS 8
#define CHUNK  2

typedef float vfloat4 __attribute__((ext_vector_type(4)));

__device__ __forceinline__ int xcc_id() {
    int x;
    asm volatile("s_getreg_b32 %0, hwreg(HW_REG_XCC_ID)" : "=s"(x));
    return x & 7;
}

// ---------- pass 0: zero counts[8] + heads[8] ----------
__global__ void zero_meta(int* __restrict__ meta) {
    if ((int)threadIdx.x < 16) meta[threadIdx.x] = 0;
}

// ---------- pass 1: bin rows into 8 band queues ----------
__global__ __launch_bounds__(256) void bin_rows(
    const float* __restrict__ rois,
    int* __restrict__ counts,          // [8]
    int* __restrict__ slots,           // [8][CAP]
    int H, int N, int CAP)
{
    const int rows_per_batch = N * POOL;
    const int total = 2 * rows_per_batch;
    const int gid = blockIdx.x * 256 + threadIdx.x;
    if (gid >= total) return;

    const int b   = gid / rows_per_batch;
    const int rem = gid - b * rows_per_batch;
    const int n   = rem / POOL;
    const int py  = rem - n * POOL;

    const float* r = rois + ((long long)b * N + n) * 4;
    const float ry1 = r[0], ry2 = r[2];

    const float fy  = (float)py * (1.0f / (POOL - 1));
    const float ys  = (ry1 + fy * (ry2 - ry1)) * (float)(H - 1);
    const float y0f = fminf(fmaxf(floorf(ys), 0.0f), (float)(H - 1));
    const int   y0  = (int)y0f;

    const int band = (b << 2) | (y0 >> 4);     // locality hint only
    const int idx  = atomicAdd(&counts[band], 1);   // idx < CAP by construction
    slots[band * CAP + idx] = gid;
}

// ---------- pass 2: persistent consume, own-band-first + stealing ----------
__global__ __launch_bounds__(256) void roialign_banded(
    const float* __restrict__ feat,    // [B,H,W,C]
    const float* __restrict__ rois,    // [B,N,4]
    float* __restrict__ out,           // [B,N,POOL,POOL,C]
    const int* __restrict__ counts,    // [8]
    int* __restrict__ heads,           // [8]
    const int* __restrict__ slots,     // [8][CAP]
    int H, int W, int C4, int N, int CAP)
{
    const int lane = threadIdx.x & 63;
    const int xcc  = xcc_id();
    const int rows_per_batch = N * POOL;

    for (int pass = 0; pass < NBANDS; ++pass) {
        const int band = (xcc + pass) & 7;
        const int cnt  = counts[band];

        while (true) {
            // cheap monotonic pre-check: stale reads only UNDER-estimate,
            // so we never skip work; we just avoid wasted atomics on
            // drained queues.
            if (((const volatile int*)heads)[band] >= cnt) break;

            int base = 0;
            if (lane == 0) base = atomicAdd(&heads[band], CHUNK);
            base = __shfl(base, 0);
            if (base >= cnt) break;
            const int end = min(base + CHUNK, cnt);

            for (int i = base; i < end; ++i) {
                const int gid = slots[band * CAP + i];
                const int b   = gid / rows_per_batch;
                const int rem = gid - b * rows_per_batch;
                const int n   = rem / POOL;
                const int py  = rem - n * POOL;

                const float* r = rois + ((long long)b * N + n) * 4;
                const float ry1 = r[0], rx1 = r[1], ry2 = r[2], rx2 = r[3];

                const float fy  = (float)py * (1.0f / (POOL - 1));
                const float ys  = (ry1 + fy * (ry2 - ry1)) * (float)(H - 1);
                const float y0f = fminf(fmaxf(floorf(ys), 0.0f), (float)(H - 1));
                const int   y0  = (int)y0f;
                const int   y1i = min(y0 + 1, H - 1);
                const float wy  = ys - y0f;

                const vfloat4* fb = (const vfloat4*)feat + (long long)b * H * W * C4;
                const vfloat4* r0 = fb + (long long)y0  * W * C4 + lane;
                const vfloat4* r1 = fb + (long long)y1i * W * C4 + lane;

                vfloat4* ob = (vfloat4*)out +
                    (((long long)b * N + n) * (POOL * POOL) + (long long)py * POOL) * C4 + lane;

                const float dx = rx2 - rx1;

#pragma unroll
                for (int px = 0; px < POOL; ++px) {
                    const float fx  = (float)px * (1.0f / (POOL - 1));
                    const float xs  = (rx1 + fx * dx) * (float)(W - 1);
                    const float x0f = fminf(fmaxf(floorf(xs), 0.0f), (float)(W - 1));
                    const int   x0  = (int)x0f;
                    const int   x1i = min(x0 + 1, W - 1);
                    const float wx  = xs - x0f;

                    const vfloat4 f00 = r0[x0  * C4];
                    const vfloat4 f01 = r0[x1i * C4];
                    const vfloat4 f10 = r1[x0  * C4];
                    const vfloat4 f11 = r1[x1i * C4];

                    const vfloat4 top = f00 + (f01 - f00) * wx;
                    const vfloat4 bot = f10 + (f11 - f10) * wx;
                    const vfloat4 o   = top + (bot - top) * wy;

                    __builtin_nontemporal_store(o, ob + px * C4);
                }
            }
        }
    }
}

// ---------- fallback: proven direct kernel (R2 structure, ~91 us) ----------
__global__ __launch_bounds__(256) void roialign_direct(
    const float* __restrict__ feat, const float* __restrict__ rois,
    float* __restrict__ out, int H, int W, int C4, int N, int blocks_per_batch)
{
    const int lane = threadIdx.x & 63;
    const int wid  = threadIdx.x >> 6;
    const int xcd  = blockIdx.x & 7;
    const int slot = blockIdx.x >> 3;
    const int b    = xcd >> 2;
    const int lblock = slot * 4 + (xcd & 3);
    if (lblock >= blocks_per_batch) return;
    const int row = lblock * 4 + wid;
    if (row >= N * POOL) return;
    const int n  = row / POOL;
    const int py = row - n * POOL;

    const float* r = rois + ((long long)b * N + n) * 4;
    const float ry1 = r[0], rx1 = r[1], ry2 = r[2], rx2 = r[3];
    const float fy  = (float)py * (1.0f / (POOL - 1));
    const float ys  = (ry1 + fy * (ry2 - ry1)) * (float)(H - 1);
    const float y0f = fminf(fmaxf(floorf(ys), 0.0f), (float)(H - 1));
    const int   y0  = (int)y0f;
    const int   y1i = min(y0 + 1, H - 1);
    const float wy  = ys - y0f;

    const vfloat4* fb = (const vfloat4*)feat + (long long)b * H * W * C4;
    const vfloat4* r0 = fb + (long long)y0  * W * C4 + lane;
    const vfloat4* r1 = fb + (long long)y1i * W * C4 + lane;
    vfloat4* ob = (vfloat4*)out +
        (((long long)b * N + n) * (POOL * POOL) + (long long)py * POOL) * C4 + lane;
    const float dx = rx2 - rx1;
#pragma unroll
    for (int px = 0; px < POOL; ++px) {
        const float fx  = (float)px * (1.0f / (POOL - 1));
        const float xs  = (rx1 + fx * dx) * (float)(W - 1);
        const float x0f = fminf(fmaxf(floorf(xs), 0.0f), (float)(W - 1));
        const int   x0  = (int)x0f;
        const int   x1i = min(x0 + 1, W - 1);
        const float wx  = xs - x0f;
        const vfloat4 f00 = r0[x0  * C4];
        const vfloat4 f01 = r0[x1i * C4];
        const vfloat4 f10 = r1[x0  * C4];
        const vfloat4 f11 = r1[x1i * C4];
        const vfloat4 top = f00 + (f01 - f00) * wx;
        const vfloat4 bot = f10 + (f11 - f10) * wx;
        const vfloat4 o   = top + (bot - top) * wy;
        __builtin_nontemporal_store(o, ob + px * C4);
    }
}

extern "C" void kernel_launch(void* const* d_in, const int* in_sizes, int n_in,
                              void* d_out, int out_size, void* d_ws, size_t ws_size,
                              hipStream_t stream) {
    const int B = 2, H = 64, W = 64, C = 256;
    const int N = in_sizes[1] / (B * 4);   // rois flat = B*N*4

    const float* feat = (const float*)d_in[0];
    const float* rois = (const float*)d_in[1];
    float* out = (float*)d_out;

    const int rows_per_batch = N * POOL;               // 14000
    const int CAP   = rows_per_batch;                  // hard per-band bound
    const int total = B * rows_per_batch;              // 28000

    const size_t ws_needed = 64 * 4                    // counts[8]+heads[8]+pad
                           + (size_t)NBANDS * CAP * 4; // slots (~448 KB)

    if (ws_size >= ws_needed && d_ws != nullptr) {
        int* counts = (int*)d_ws;           // [0,8)
        int* heads  = counts + 8;           // [8,16)
        int* slots  = counts + 64;          // aligned

        const int bin_blocks = (total + 255) / 256;    // 110

        zero_meta<<<1, 64, 0, stream>>>(counts);
        bin_rows<<<bin_blocks, 256, 0, stream>>>(rois, counts, slots, H, N, CAP);
        roialign_banded<<<2048, 256, 0, stream>>>(
            feat, rois, out, counts, heads, slots, H, W, C / 4, N, CAP);
    } else {
        const int blocks_per_batch = (rows_per_batch + 3) / 4;
        const int slots_g = (blocks_per_batch + 3) / 4;
        roialign_direct<<<slots_g * 8, 256, 0, stream>>>(
            feat, rois, out, H, W, C / 4, N, blocks_per_batch);
    }
}

// Round 6
// 265.979 us; speedup vs baseline: 4.5645x; 4.5645x over previous
//
#include <hip/hip_runtime.h>

// RoiAlign (TF crop_and_resize style), fp32, NHWC.
// features: [B,H,W,C] = [2,64,64,256]; rois: [B,N,4] = [2,2000,4]
// out: [B,N,7,7,C]
//
// R7: XCC-ID band queues, contention-fixed.
// R6 post-mortem: XCC-bound banding PROVED the read-locality theory --
// consume FETCH_SIZE dropped to 10.7 MB (compulsory-only; was ~780 MB
// implied) -- but ran 869us at 1.9% VALUBusy because counts[8]/heads[8]
// shared single cache lines: 14000 wave-level pops + volatile polling +
// 28000 binning atomics all ping-ponged two lines device-wide.
// Fixes (architecture unchanged):
//   1. every counter padded to its own 128B line (band*32 ints)
//   2. bin_rows aggregates per-block in LDS -> 8 global atomics/block
//      (880 total), slot = global_base + local_pos
//   3. consume pops per BLOCK (thread 0, CHUNK=8, LDS broadcast,
//      4 waves x 2 rows) -> 3500 pops total, ~440/padded-counter;
//      monotonic pre-check load is safe (stale = under-estimate)
// Correctness: band is a pure locality hint; slots store global row id;
// consume recomputes everything; stealing covers any XCD imbalance or
// bogus XCC_ID. Inner row body bit-identical to R2; nt stores kept.
// Fallback to proven R2 direct kernel if ws too small.

#define POOL   7
#define NBANDS 8
#define PAD    32          // ints -> 128 B per counter
#define CHUNK  8           // rows per block pop (4 waves x 2 rows)

typedef float vfloat4 __attribute__((ext_vector_type(4)));

__device__ __forceinline__ int xcc_id() {
    int x;
    asm volatile("s_getreg_b32 %0, hwreg(HW_REG_XCC_ID)" : "=s"(x));
    return x & 7;
}

// ---------- pass 0: zero meta (counts + heads, padded) ----------
__global__ void zero_meta(int* __restrict__ meta) {
    meta[threadIdx.x] = 0;          // 512 ints
}

// ---------- pass 1: bin rows into 8 band queues (LDS-aggregated) ----------
__global__ __launch_bounds__(256) void bin_rows(
    const float* __restrict__ rois,
    int* __restrict__ counts,          // counts[band*PAD]
    int* __restrict__ slots,           // [8][CAP]
    int H, int N, int CAP)
{
    __shared__ int lcnt[NBANDS];
    __shared__ int lbase[NBANDS];

    const int rows_per_batch = N * POOL;
    const int total = 2 * rows_per_batch;
    const int gid = blockIdx.x * 256 + threadIdx.x;

    if (threadIdx.x < NBANDS) lcnt[threadIdx.x] = 0;
    __syncthreads();

    int band = 0, pos = 0;
    bool valid = (gid < total);
    if (valid) {
        const int b   = gid / rows_per_batch;
        const int rem = gid - b * rows_per_batch;
        const int n   = rem / POOL;
        const int py  = rem - n * POOL;

        const float* r = rois + ((long long)b * N + n) * 4;
        const float ry1 = r[0], ry2 = r[2];

        const float fy  = (float)py * (1.0f / (POOL - 1));
        const float ys  = (ry1 + fy * (ry2 - ry1)) * (float)(H - 1);
        const float y0f = fminf(fmaxf(floorf(ys), 0.0f), (float)(H - 1));
        const int   y0  = (int)y0f;

        band = ((gid >= rows_per_batch) ? 4 : 0) | (y0 >> 4);
        pos  = atomicAdd(&lcnt[band], 1);          // LDS atomic: fast
    }
    __syncthreads();
    if (threadIdx.x < NBANDS && lcnt[threadIdx.x] > 0)
        lbase[threadIdx.x] = atomicAdd(&counts[threadIdx.x * PAD], lcnt[threadIdx.x]);
    __syncthreads();
    if (valid)
        slots[band * CAP + lbase[band] + pos] = gid;
}

// ---------- pass 2: consume, own-band-first + block-granular stealing ----------
__global__ __launch_bounds__(256) void roialign_banded(
    const float* __restrict__ feat,    // [B,H,W,C]
    const float* __restrict__ rois,    // [B,N,4]
    float* __restrict__ out,           // [B,N,POOL,POOL,C]
    const int* __restrict__ counts,    // counts[band*PAD]
    int* __restrict__ heads,           // heads[band*PAD]
    const int* __restrict__ slots,     // [8][CAP]
    int H, int W, int C4, int N, int CAP)
{
    __shared__ int sbase;

    const int lane = threadIdx.x & 63;
    const int wid  = threadIdx.x >> 6;             // wave 0..3
    const int xcc  = xcc_id();
    const int rows_per_batch = N * POOL;

    for (int pass = 0; pass < NBANDS; ++pass) {
        const int band = (xcc + pass) & 7;
        const int cnt  = counts[band * PAD];       // stable after pass 1

        while (true) {
            __syncthreads();                       // sbase reuse barrier
            if (threadIdx.x == 0) {
                // monotonic pre-check: stale read only under-estimates,
                // so a skipped atomic is never a skipped row.
                const int h = ((const volatile int*)heads)[band * PAD];
                sbase = (h >= cnt) ? cnt : atomicAdd(&heads[band * PAD], CHUNK);
            }
            __syncthreads();
            const int base = sbase;                // block-uniform
            if (base >= cnt) break;

#pragma unroll
            for (int k = 0; k < CHUNK / 4; ++k) {  // 2 rows per wave
                const int i = base + wid * (CHUNK / 4) + k;
                if (i >= cnt) continue;

                const int gid = slots[band * CAP + i];
                const int b   = gid / rows_per_batch;
                const int rem = gid - b * rows_per_batch;
                const int n   = rem / POOL;
                const int py  = rem - n * POOL;

                const float* r = rois + ((long long)b * N + n) * 4;
                const float ry1 = r[0], rx1 = r[1], ry2 = r[2], rx2 = r[3];

                const float fy  = (float)py * (1.0f / (POOL - 1));
                const float ys  = (ry1 + fy * (ry2 - ry1)) * (float)(H - 1);
                const float y0f = fminf(fmaxf(floorf(ys), 0.0f), (float)(H - 1));
                const int   y0  = (int)y0f;
                const int   y1i = min(y0 + 1, H - 1);
                const float wy  = ys - y0f;

                const vfloat4* fb = (const vfloat4*)feat + (long long)b * H * W * C4;
                const vfloat4* r0 = fb + (long long)y0  * W * C4 + lane;
                const vfloat4* r1 = fb + (long long)y1i * W * C4 + lane;

                vfloat4* ob = (vfloat4*)out +
                    (((long long)b * N + n) * (POOL * POOL) + (long long)py * POOL) * C4 + lane;

                const float dx = rx2 - rx1;

#pragma unroll
                for (int px = 0; px < POOL; ++px) {
                    const float fx  = (float)px * (1.0f / (POOL - 1));
                    const float xs  = (rx1 + fx * dx) * (float)(W - 1);
                    const float x0f = fminf(fmaxf(floorf(xs), 0.0f), (float)(W - 1));
                    const int   x0  = (int)x0f;
                    const int   x1i = min(x0 + 1, W - 1);
                    const float wx  = xs - x0f;

                    const vfloat4 f00 = r0[x0  * C4];
                    const vfloat4 f01 = r0[x1i * C4];
                    const vfloat4 f10 = r1[x0  * C4];
                    const vfloat4 f11 = r1[x1i * C4];

                    const vfloat4 top = f00 + (f01 - f00) * wx;
                    const vfloat4 bot = f10 + (f11 - f10) * wx;
                    const vfloat4 o   = top + (bot - top) * wy;

                    __builtin_nontemporal_store(o, ob + px * C4);
                }
            }
        }
    }
}

// ---------- fallback: proven direct kernel (R2 structure, ~91 us) ----------
__global__ __launch_bounds__(256) void roialign_direct(
    const float* __restrict__ feat, const float* __restrict__ rois,
    float* __restrict__ out, int H, int W, int C4, int N, int blocks_per_batch)
{
    const int lane = threadIdx.x & 63;
    const int wid  = threadIdx.x >> 6;
    const int xcd  = blockIdx.x & 7;
    const int slot = blockIdx.x >> 3;
    const int b    = xcd >> 2;
    const int lblock = slot * 4 + (xcd & 3);
    if (lblock >= blocks_per_batch) return;
    const int row = lblock * 4 + wid;
    if (row >= N * POOL) return;
    const int n  = row / POOL;
    const int py = row - n * POOL;

    const float* r = rois + ((long long)b * N + n) * 4;
    const float ry1 = r[0], rx1 = r[1], ry2 = r[2], rx2 = r[3];
    const float fy  = (float)py * (1.0f / (POOL - 1));
    const float ys  = (ry1 + fy * (ry2 - ry1)) * (float)(H - 1);
    const float y0f = fminf(fmaxf(floorf(ys), 0.0f), (float)(H - 1));
    const int   y0  = (int)y0f;
    const int   y1i = min(y0 + 1, H - 1);
    const float wy  = ys - y0f;

    const vfloat4* fb = (const vfloat4*)feat + (long long)b * H * W * C4;
    const vfloat4* r0 = fb + (long long)y0  * W * C4 + lane;
    const vfloat4* r1 = fb + (long long)y1i * W * C4 + lane;
    vfloat4* ob = (vfloat4*)out +
        (((long long)b * N + n) * (POOL * POOL) + (long long)py * POOL) * C4 + lane;
    const float dx = rx2 - rx1;
#pragma unroll
    for (int px = 0; px < POOL; ++px) {
        const float fx  = (float)px * (1.0f / (POOL - 1));
        const float xs  = (rx1 + fx * dx) * (float)(W - 1);
        const float x0f = fminf(fmaxf(floorf(xs), 0.0f), (float)(W - 1));
        const int   x0  = (int)x0f;
        const int   x1i = min(x0 + 1, W - 1);
        const float wx  = xs - x0f;
        const vfloat4 f00 = r0[x0  * C4];
        const vfloat4 f01 = r0[x1i * C4];
        const vfloat4 f10 = r1[x0  * C4];
        const vfloat4 f11 = r1[x1i * C4];
        const vfloat4 top = f00 + (f01 - f00) * wx;
        const vfloat4 bot = f10 + (f11 - f10) * wx;
        const vfloat4 o   = top + (bot - top) * wy;
        __builtin_nontemporal_store(o, ob + px * C4);
    }
}

extern "C" void kernel_launch(void* const* d_in, const int* in_sizes, int n_in,
                              void* d_out, int out_size, void* d_ws, size_t ws_size,
                              hipStream_t stream) {
    const int B = 2, H = 64, W = 64, C = 256;
    const int N = in_sizes[1] / (B * 4);   // rois flat = B*N*4

    const float* feat = (const float*)d_in[0];
    const float* rois = (const float*)d_in[1];
    float* out = (float*)d_out;

    const int rows_per_batch = N * POOL;               // 14000
    const int CAP   = rows_per_batch;                  // hard per-band bound
    const int total = B * rows_per_batch;              // 28000

    const size_t ws_needed = 1024 * 4                  // padded meta
                           + (size_t)NBANDS * CAP * 4; // slots (~448 KB)

    if (ws_size >= ws_needed && d_ws != nullptr) {
        int* counts = (int*)d_ws;            // counts[band*PAD], bands 0..7
        int* heads  = counts + NBANDS * PAD; // heads[band*PAD]
        int* slots  = counts + 1024;         // after padded meta

        const int bin_blocks = (total + 255) / 256;    // 110

        zero_meta<<<1, 512, 0, stream>>>(counts);
        bin_rows<<<bin_blocks, 256, 0, stream>>>(rois, counts, slots, H, N, CAP);
        roialign_banded<<<2048, 256, 0, stream>>>(
            feat, rois, out, counts, heads, slots, H, W, C / 4, N, CAP);
    } else {
        const int blocks_per_batch = (rows_per_batch + 3) / 4;
        const int slots_g = (blocks_per_batch + 3) / 4;
        roialign_direct<<<slots_g * 8, 256, 0, stream>>>(
            feat, rois, out, H, W, C / 4, N, blocks_per_batch);
    }
}

// Round 8
// 218.551 us; speedup vs baseline: 5.5551x; 1.2170x over previous
//
#include <hip/hip_runtime.h>

// RoiAlign (TF crop_and_resize style), fp32, NHWC.
// features: [B,H,W,C] = [2,64,64,256]; rois: [B,N,4] = [2,2000,4]
// out: [B,N,7,7,C]
//
// R8 re-run (R7 submission died on container acquire -- infra, not kernel):
// revert to the proven direct-gather structure (R2, ~91us kernel, 216us
// dur incl ~126us harness fill), minus the blockIdx%8 "XCD swizzle"
// (R3 proved the %8->XCD mapping assumption false; linear mapping also
// keeps consecutive blocks in the same batch).
//
// Why direct gather: rounds R3-R7 attacked read locality three ways
// (static y-banding, global sort + sliding window, true XCC_ID-bound
// work queues). R6 proved banding reaches compulsory-only read traffic
// (FETCH 10.7 MB), yet NO locality scheme beat the gather kernel:
// locality is worth ~0 here because the 8 MB feature array is always
// L3-resident (FETCH_SIZE counts HBM only -- the "784 MB HBM reads"
// premise was never true), and the kernel sits near its vmem-path /
// latency-hiding equilibrium at full occupancy (VGPR<=64 -> 8 waves/EU,
// 32 waves/CU). Every indirection scheme paid 12-50us of tax for that ~0.
//
// Structure: one wave (64 lanes) per output ROW (b,n,py); px=0..6 loop:
// 4 coalesced 1KB corner loads + vfloat4 lerp + 1 nontemporal 1KB store.
// nt stores keep the 196 MB write stream from polluting caches (R2-proven).

#define POOL 7

typedef float vfloat4 __attribute__((ext_vector_type(4)));

__global__ __launch_bounds__(256) void roialign_kernel(
    const float* __restrict__ feat,   // [B,H,W,C]
    const float* __restrict__ rois,   // [B,N,4]
    float* __restrict__ out,          // [B,N,POOL,POOL,C]
    int H, int W, int C4, int N, int total)
{
    const int lane = threadIdx.x & 63;
    const int wid  = threadIdx.x >> 6;        // wave in block (0..3)

    const int gid = blockIdx.x * 4 + wid;     // global output row (b,n,py)
    if (gid >= total) return;

    const int rows_per_batch = N * POOL;
    const int b   = (gid >= rows_per_batch) ? 1 : 0;
    const int rem = gid - b * rows_per_batch;
    const int n   = rem / POOL;
    const int py  = rem - n * POOL;

    // ROI load: one dwordx4, all lanes same address -> broadcast from L2
    const vfloat4 rv = *(const vfloat4*)(rois + ((long long)b * N + n) * 4);
    const float ry1 = rv.x, rx1 = rv.y, ry2 = rv.z, rx2 = rv.w;

    // y interpolation (row-uniform)
    const float fy  = (float)py * (1.0f / (POOL - 1));
    const float ys  = (ry1 + fy * (ry2 - ry1)) * (float)(H - 1);
    const float y0f = fminf(fmaxf(floorf(ys), 0.0f), (float)(H - 1));
    const int   y0  = (int)y0f;
    const int   y1i = min(y0 + 1, H - 1);
    const float wy  = ys - y0f;

    const vfloat4* fb = (const vfloat4*)feat + (long long)b * H * W * C4;
    const vfloat4* r0 = fb + (long long)y0  * W * C4 + lane;
    const vfloat4* r1 = fb + (long long)y1i * W * C4 + lane;

    vfloat4* ob = (vfloat4*)out +
                  (((long long)b * N + n) * (POOL * POOL) + (long long)py * POOL) * C4 + lane;

    const float dx = rx2 - rx1;

#pragma unroll
    for (int px = 0; px < POOL; ++px) {
        const float fx  = (float)px * (1.0f / (POOL - 1));
        const float xs  = (rx1 + fx * dx) * (float)(W - 1);
        const float x0f = fminf(fmaxf(floorf(xs), 0.0f), (float)(W - 1));
        const int   x0  = (int)x0f;
        const int   x1i = min(x0 + 1, W - 1);
        const float wx  = xs - x0f;

        const vfloat4 f00 = r0[x0  * C4];
        const vfloat4 f01 = r0[x1i * C4];
        const vfloat4 f10 = r1[x0  * C4];
        const vfloat4 f11 = r1[x1i * C4];

        const vfloat4 top = f00 + (f01 - f00) * wx;
        const vfloat4 bot = f10 + (f11 - f10) * wx;
        const vfloat4 o   = top + (bot - top) * wy;

        __builtin_nontemporal_store(o, ob + px * C4);
    }
}

extern "C" void kernel_launch(void* const* d_in, const int* in_sizes, int n_in,
                              void* d_out, int out_size, void* d_ws, size_t ws_size,
                              hipStream_t stream) {
    const int B = 2, H = 64, W = 64, C = 256;
    const int N = in_sizes[1] / (B * 4);   // rois flat = B*N*4

    const float* feat = (const float*)d_in[0];
    const float* rois = (const float*)d_in[1];
    float* out = (float*)d_out;

    const int total  = B * N * POOL;            // 28000 output rows
    const int blocks = (total + 3) / 4;         // 7000 (4 waves/block)

    roialign_kernel<<<blocks, 256, 0, stream>>>(feat, rois, out,
                                                H, W, C / 4, N, total);
}